// Round 1
// baseline (230.788 us; speedup 1.0000x reference)
//
#include <hip/hip_runtime.h>
#include <math.h>

#define IMG_H 2048
#define IMG_W 2048
#define NB    8
#define BORDER 10
#define REP_THR 0.6f

// One thread handles 4 consecutive pixels in a row (float4 in/out).
// W/4 = 512 thread-columns per row; 2048 rows; 8 images.
// BORDER=10 > 1, so any pixel needing out-of-bounds neighbors is in the
// zeroed border frame -> interior pixels do unguarded 3x3 loads.
__global__ __launch_bounds__(256) void nms_kernel(const float* __restrict__ in,
                                                  float* __restrict__ out) {
    const int tid = blockIdx.x * blockDim.x + threadIdx.x;   // < 8*2048*512 = 2^23
    const int x4 = (tid & 511) << 2;          // 0,4,...,2044
    const int y  = (tid >> 9) & (IMG_H - 1);  // 0..2047
    const int b  = tid >> 20;                 // image index

    const size_t img_off = (size_t)b * IMG_H * IMG_W;
    float* o = out + img_off + (size_t)y * IMG_W + x4;

    // Rows fully inside the border frame, and the two edge column-groups
    // (cols 0..3 and 2044..2047 are all < 10 or >= 2038): pure zeros.
    if (y < BORDER || y >= IMG_H - BORDER || x4 == 0 || x4 == IMG_W - 4) {
        *(float4*)o = make_float4(0.f, 0.f, 0.f, 0.f);
        return;
    }

    const float* rm = in + img_off + (size_t)(y - 1) * IMG_W + x4;
    const float* rc = in + img_off + (size_t)y       * IMG_W + x4;
    const float* rp = in + img_off + (size_t)(y + 1) * IMG_W + x4;

    const float4 cm = *(const float4*)rm;
    const float4 cc = *(const float4*)rc;
    const float4 cp = *(const float4*)rp;

    const float lm = rm[-1], qm = rm[4];
    const float lc = rc[-1], qc = rc[4];
    const float lp = rp[-1], qp = rp[4];

    // Horizontal 3-max per row
    const float hm0 = fmaxf(lm,   fmaxf(cm.x, cm.y));
    const float hm1 = fmaxf(cm.x, fmaxf(cm.y, cm.z));
    const float hm2 = fmaxf(cm.y, fmaxf(cm.z, cm.w));
    const float hm3 = fmaxf(cm.z, fmaxf(cm.w, qm));

    const float hc0 = fmaxf(lc,   fmaxf(cc.x, cc.y));
    const float hc1 = fmaxf(cc.x, fmaxf(cc.y, cc.z));
    const float hc2 = fmaxf(cc.y, fmaxf(cc.z, cc.w));
    const float hc3 = fmaxf(cc.z, fmaxf(cc.w, qc));

    const float hp0 = fmaxf(lp,   fmaxf(cp.x, cp.y));
    const float hp1 = fmaxf(cp.x, fmaxf(cp.y, cp.z));
    const float hp2 = fmaxf(cp.y, fmaxf(cp.z, cp.w));
    const float hp3 = fmaxf(cp.z, fmaxf(cp.w, qp));

    // Vertical 3-max -> local 3x3 max (includes center)
    const float m0 = fmaxf(hm0, fmaxf(hc0, hp0));
    const float m1 = fmaxf(hm1, fmaxf(hc1, hp1));
    const float m2 = fmaxf(hm2, fmaxf(hc2, hp2));
    const float m3 = fmaxf(hm3, fmaxf(hc3, hp3));

    // Column border mask per lane
    const bool bx0 = (x4 + 0 >= BORDER) && (x4 + 0 < IMG_W - BORDER);
    const bool bx1 = (x4 + 1 >= BORDER) && (x4 + 1 < IMG_W - BORDER);
    const bool bx2 = (x4 + 2 >= BORDER) && (x4 + 2 < IMG_W - BORDER);
    const bool bx3 = (x4 + 3 >= BORDER) && (x4 + 3 < IMG_W - BORDER);

    float4 r;
    r.x = (cc.x == m0 && cc.x >= REP_THR && bx0) ? 1.f : 0.f;
    r.y = (cc.y == m1 && cc.y >= REP_THR && bx1) ? 1.f : 0.f;
    r.z = (cc.z == m2 && cc.z >= REP_THR && bx2) ? 1.f : 0.f;
    r.w = (cc.w == m3 && cc.w >= REP_THR && bx3) ? 1.f : 0.f;

    *(float4*)o = r;
}

extern "C" void kernel_launch(void* const* d_in, const int* in_sizes, int n_in,
                              void* d_out, int out_size, void* d_ws, size_t ws_size,
                              hipStream_t stream) {
    const float* in = (const float*)d_in[0];
    float* out = (float*)d_out;
    const int total_threads = NB * IMG_H * (IMG_W / 4);  // 2^23
    const int block = 256;
    const int grid = total_threads / block;              // 32768
    nms_kernel<<<grid, block, 0, stream>>>(in, out);
}

// Round 2
// 226.523 us; speedup vs baseline: 1.0188x; 1.0188x over previous
//
#include <hip/hip_runtime.h>
#include <math.h>

#define IMG_H 2048
#define IMG_W 2048
#define NB    8
#define BORDER 10
#define REP_THR 0.6f

// Each thread computes a 4-row x 4-col output patch (float4 per row).
// Loads 6 input rows (y0-1 .. y0+4) once each into registers, computes the
// horizontal 3-max per row once, then slides the vertical 3-max window.
// BORDER=10 > stencil radius 1, so all out-of-bounds-needing pixels are in
// the zeroed border frame -> interior loads are unguarded.
//
// Mapping: gx = 4-col group (512), gy = 4-row group (512), b = image (8).
// gy in {0,1,510,511} (rows 0-7, 2040-2047) and gx in {0,511} are pure-zero
// patches. gy=2 / gy=509 patches are computed but row-masked (rows 8,9 /
// 2038,2039 forced to 0).
__global__ __launch_bounds__(256) void nms_kernel(const float* __restrict__ in,
                                                  float* __restrict__ out) {
    const int tid = blockIdx.x * blockDim.x + threadIdx.x;  // < 8*512*512 = 2^21
    const int gx = tid & 511;
    const int gy = (tid >> 9) & 511;
    const int b  = tid >> 18;

    const int x4 = gx << 2;   // 0..2044
    const int y0 = gy << 2;   // 0..2044

    const size_t img_off = (size_t)b * IMG_H * IMG_W;
    float* obase = out + img_off + (size_t)y0 * IMG_W + x4;

    // Fully-border patches: 4 rows of zeros, no loads.
    if (y0 + 4 <= BORDER || y0 >= IMG_H - BORDER || gx == 0 || gx == 511) {
        const float4 z = make_float4(0.f, 0.f, 0.f, 0.f);
        *(float4*)(obase + 0 * IMG_W) = z;
        *(float4*)(obase + 1 * IMG_W) = z;
        *(float4*)(obase + 2 * IMG_W) = z;
        *(float4*)(obase + 3 * IMG_W) = z;
        return;
    }

    const float* base = in + img_off + (size_t)(y0 - 1) * IMG_W + x4;

    float4 h[6];   // horizontal 3-max of rows y0-1 .. y0+4
    float4 c[4];   // center values of rows y0 .. y0+3
#pragma unroll
    for (int r = 0; r < 6; ++r) {
        const float* row = base + (size_t)r * IMG_W;
        const float4 v = *(const float4*)row;
        const float  l = row[-1];
        const float  q = row[4];
        float4 hh;
        hh.x = fmaxf(l,   fmaxf(v.x, v.y));
        hh.y = fmaxf(v.x, fmaxf(v.y, v.z));
        hh.z = fmaxf(v.y, fmaxf(v.z, v.w));
        hh.w = fmaxf(v.z, fmaxf(v.w, q));
        h[r] = hh;
        if (r >= 1 && r <= 4) c[r - 1] = v;
    }

    // Column border mask (uniform across the 4 rows)
    const bool bx0 = (x4 + 0 >= BORDER) && (x4 + 0 < IMG_W - BORDER);
    const bool bx1 = (x4 + 1 >= BORDER) && (x4 + 1 < IMG_W - BORDER);
    const bool bx2 = (x4 + 2 >= BORDER) && (x4 + 2 < IMG_W - BORDER);
    const bool bx3 = (x4 + 3 >= BORDER) && (x4 + 3 < IMG_W - BORDER);

#pragma unroll
    for (int j = 0; j < 4; ++j) {
        const int y = y0 + j;
        const bool rowok = (y >= BORDER) && (y < IMG_H - BORDER);

        float4 m;
        m.x = fmaxf(h[j].x, fmaxf(h[j + 1].x, h[j + 2].x));
        m.y = fmaxf(h[j].y, fmaxf(h[j + 1].y, h[j + 2].y));
        m.z = fmaxf(h[j].z, fmaxf(h[j + 1].z, h[j + 2].z));
        m.w = fmaxf(h[j].w, fmaxf(h[j + 1].w, h[j + 2].w));

        float4 r;
        r.x = (c[j].x == m.x && c[j].x >= REP_THR && bx0 && rowok) ? 1.f : 0.f;
        r.y = (c[j].y == m.y && c[j].y >= REP_THR && bx1 && rowok) ? 1.f : 0.f;
        r.z = (c[j].z == m.z && c[j].z >= REP_THR && bx2 && rowok) ? 1.f : 0.f;
        r.w = (c[j].w == m.w && c[j].w >= REP_THR && bx3 && rowok) ? 1.f : 0.f;

        *(float4*)(obase + (size_t)j * IMG_W) = r;
    }
}

extern "C" void kernel_launch(void* const* d_in, const int* in_sizes, int n_in,
                              void* d_out, int out_size, void* d_ws, size_t ws_size,
                              hipStream_t stream) {
    const float* in = (const float*)d_in[0];
    float* out = (float*)d_out;
    const int total_threads = NB * (IMG_H / 4) * (IMG_W / 4);  // 2^21
    const int block = 256;
    const int grid = total_threads / block;                    // 8192
    nms_kernel<<<grid, block, 0, stream>>>(in, out);
}